// Round 6
// baseline (2394.005 us; speedup 1.0000x reference)
//
#include <hip/hip_runtime.h>

// ECGLSTM: B=256, T=5000, input_size=1, H=64, fused FC(64->128)+ReLU.
// R9: R7 quad layout + DPP row_ror dot + __launch_bounds__(256,1).
//   - ROOT CAUSE found in R5/R7/R8: plain __launch_bounds__(256) made the
//     compiler cap VGPRs at ~48, so the 64-float weight array was NEVER
//     register-resident -- it was re-loaded from L1/L2 every step (no spill
//     in WRITE_SIZE, but per-step VMEM latency). (256,1) unlocks the budget.
//   - Dot: per step each lane reads 4 LDS "bases" h[lane^{0,16,32,48}]
//     (conflict-free b32), then reaches the other 60 h values with
//     register-only DPP row_ror:1..15 on the bases (GCNDPPCombine can fuse
//     the mov_dpp into v_fmac). Zero readlane hazards, zero per-k LDS.
//   - Weights gathered ONCE at init in rotation order:
//       wrot[16c+j] = W[row][ ((lane&48)|((lane+e*j)&15)) ^ 16c ]
//     where e = hardware ror direction, resolved by a runtime probe
//     (ror:1 on laneid + readlane) -> correctness independent of DPP
//     direction convention.
//   - Gate exchange stays in-register via quad_perm (proven in R7).
//   - LDS per wave per step: 4 base reads + 1 xv read + 1 masked h write,
//     ONE barrier. Double-buffered hbuf makes one barrier sufficient.

#define LSTM_H 64
#define LSTM_T 5000
#define LSTM_B 256

__device__ __forceinline__ float fast_rcp(float v) {
    return __builtin_amdgcn_rcpf(v);
}

// Rotate within each 16-lane row by J (direction resolved at runtime by the
// probe; the weight gather uses the probed direction so pairing is correct).
template<int J>
__device__ __forceinline__ float row_ror(float v) {
    return __builtin_bit_cast(float,
        __builtin_amdgcn_mov_dpp(__builtin_bit_cast(int, v),
                                 0x120 + J, 0xF, 0xF, false));
}

// Broadcast lane (quad_base + K) to all 4 lanes of the quad (proven in R7).
template<int K>
__device__ __forceinline__ float quad_bcast(float v) {
    constexpr int ctrl = K | (K << 2) | (K << 4) | (K << 6);  // quad_perm
    return __builtin_bit_cast(float,
        __builtin_amdgcn_mov_dpp(__builtin_bit_cast(int, v),
                                 ctrl, 0xF, 0xF, false));
}

__global__ __launch_bounds__(256, 1) void ECGLSTM_lstm_dpp(
    const float* __restrict__ x,      // [B, T]
    const float* __restrict__ W_ih,   // [4H, 1]
    const float* __restrict__ W_hh,   // [4H, H]
    const float* __restrict__ b_ih,   // [4H]
    const float* __restrict__ b_hh,   // [4H]
    const float* __restrict__ W_fc,   // [128, H]
    const float* __restrict__ b_fc,   // [128]
    float* __restrict__ out)          // [B, 128]
{
    const int tid  = threadIdx.x;     // 0..255
    const int lane = tid & 63;
    const int w    = tid >> 6;        // wave 0..3
    const int g    = lane & 3;        // gate: 0=i 1=f 2=g 3=o
    const int ul   = lane >> 2;       // unit-local 0..15
    const int u    = w * 16 + ul;     // hidden unit 0..63
    const int b    = blockIdx.x;

    __shared__ float xch[LSTM_T];     // whole x row, staged once (20 KB)
    __shared__ float hbuf[2][LSTM_H]; // double-buffered h

    // Stage x (coalesced, once)
    const float* xb = x + b * LSTM_T;
    for (int i = tid; i < LSTM_T; i += 256) xch[i] = xb[i];

    // Probe the hardware row_ror direction: dst[0] = src[(0+e)&15].
    int dirp = __builtin_amdgcn_mov_dpp(lane, 0x121, 0xF, 0xF, false);
    const int e = (__builtin_amdgcn_readlane(dirp, 0) == 1) ? 1 : -1;

    // Gather W_hh row in ROTATION order (once; L2-resident, ~us).
    // At step time, chunk c / offset j delivers h[ ((lane&48)|((lane+e*j)&15)) ^ 16c ].
    const int row = g * LSTM_H + u;
    float wrot[LSTM_H];
    #pragma unroll
    for (int m = 0; m < LSTM_H; ++m) {
        const int cc = m >> 4, jj = m & 15;
        const int k  = (((lane & 48) | ((lane + e * jj) & 15)) ^ (cc << 4));
        wrot[m] = W_hh[row * LSTM_H + k];
    }

    const float wih  = W_ih[row];
    const float bias = b_ih[row] + b_hh[row];
    const bool  is_t = (g == 2);                  // tanh gate
    const float aexp = is_t ? -2.0f : -1.0f;      // ex = exp(aexp * gate)
    const float smul = is_t ?  2.0f :  1.0f;      // act = s*rcp(1+ex) + d
    const float dadd = is_t ? -1.0f :  0.0f;

    float c = 0.0f;                   // cell state, replicated across the quad
    if (tid < LSTM_H) hbuf[0][tid] = 0.0f;
    __syncthreads();                  // x staged + h0 visible

    // One chunk of the dot: base bc = h[lane^16c]; 15 DPP rotations cover
    // the rest of the 16-lane row. All indices compile-time -> registers.
    #define RF(cN, j) a##cN = fmaf(row_ror<j>(b##cN), wrot[16 * cN + j], a##cN);
    #define CHUNK(cN)                                                          \
        float a##cN = b##cN * wrot[16 * cN];                                   \
        RF(cN, 1)  RF(cN, 2)  RF(cN, 3)  RF(cN, 4)  RF(cN, 5)                  \
        RF(cN, 6)  RF(cN, 7)  RF(cN, 8)  RF(cN, 9)  RF(cN, 10)                 \
        RF(cN, 11) RF(cN, 12) RF(cN, 13) RF(cN, 14) RF(cN, 15)

    #define LSTM_STEP(t, P)                                                    \
    {                                                                          \
        const float xv = xch[(t)];                      /* broadcast b32 */    \
        const float* hb = hbuf[(P)];                                           \
        float b0 = hb[lane];                            /* conflict-free */    \
        float b1 = hb[lane ^ 16];                                              \
        float b2 = hb[lane ^ 32];                                              \
        float b3 = hb[lane ^ 48];                                              \
        CHUNK(0) CHUNK(1) CHUNK(2) CHUNK(3)                                    \
        float dot = (a0 + a1) + (a2 + a3);                                     \
        float gv  = fmaf(xv, wih, bias) + dot;                                 \
        float ex  = __expf(aexp * gv);                                         \
        float act = fmaf(smul, fast_rcp(1.0f + ex), dadd);                     \
        float i_  = quad_bcast<0>(act);                                        \
        float f_  = quad_bcast<1>(act);                                        \
        float g_  = quad_bcast<2>(act);                                        \
        float o_  = quad_bcast<3>(act);                                        \
        c = fmaf(f_, c, i_ * g_);                                              \
        float e2 = __expf(2.0f * c);                                           \
        float th = 1.0f - 2.0f * fast_rcp(e2 + 1.0f);                          \
        if (g == 0) hbuf[1 - (P)][u] = o_ * th;         /* 1 writer/unit */    \
        __syncthreads();                                /* the ONE barrier */  \
    }

    for (int t = 0; t < LSTM_T; t += 2) {
        LSTM_STEP(t, 0);
        LSTM_STEP(t + 1, 1);
    }
    #undef LSTM_STEP
    #undef CHUNK
    #undef RF

    // Final h is in hbuf[0] (T even); last step's barrier made it visible.
    // FC(64->128)+ReLU: threads 0..127 compute one output row each.
    if (tid < 128) {
        float s = b_fc[tid];
        const float4* wf = reinterpret_cast<const float4*>(W_fc + tid * LSTM_H);
        const float4* h4 = reinterpret_cast<const float4*>(hbuf[0]);
        #pragma unroll
        for (int i = 0; i < LSTM_H / 4; ++i) {
            float4 wv = wf[i];
            float4 hv = h4[i];
            s = fmaf(hv.x, wv.x, s);
            s = fmaf(hv.y, wv.y, s);
            s = fmaf(hv.z, wv.z, s);
            s = fmaf(hv.w, wv.w, s);
        }
        out[b * 128 + tid] = fmaxf(s, 0.0f);
    }
}

extern "C" void kernel_launch(void* const* d_in, const int* in_sizes, int n_in,
                              void* d_out, int out_size, void* d_ws, size_t ws_size,
                              hipStream_t stream) {
    const float* x    = (const float*)d_in[0];
    const float* W_ih = (const float*)d_in[1];
    const float* W_hh = (const float*)d_in[2];
    const float* b_ih = (const float*)d_in[3];
    const float* b_hh = (const float*)d_in[4];
    const float* W_fc = (const float*)d_in[5];
    const float* b_fc = (const float*)d_in[6];
    float* out = (float*)d_out;

    ECGLSTM_lstm_dpp<<<LSTM_B, 256, 0, stream>>>(
        x, W_ih, W_hh, b_ih, b_hh, W_fc, b_fc, out);
}